// Round 8
// baseline (400.436 us; speedup 1.0000x reference)
//
#include <hip/hip_runtime.h>

#define NN 8192
#define TT 60
#define DF 6
#define HH 64
#define GG 256   // 4*H
#define RS 132   // sorted-row stride: [0..63] u*last, [64..127] w*last, [128] u, [129] w
#define CH 32    // rows per chunk = rows per block slice
#define NB 256   // tail grid = #chunks = #blocks

typedef _Float16 half8 __attribute__((ext_vector_type(8)));
typedef float f32x4 __attribute__((ext_vector_type(4)));
#define MFMA16(a, b, c) __builtin_amdgcn_mfma_f32_16x16x32_f16((a), (b), (c), 0, 0, 0)

__device__ __forceinline__ float sigmoidf_(float x) {
    return __builtin_amdgcn_rcpf(1.0f + __expf(-x));
}
__device__ __forceinline__ float tanhf_(float x) {
    return __builtin_fmaf(2.0f, __builtin_amdgcn_rcpf(1.0f + __expf(-2.0f * x)), -1.0f);
}
__device__ __forceinline__ float lrelu_(float x) { return x > 0.0f ? x : 0.01f * x; }

__device__ __forceinline__ half8 ldw8(const float* __restrict__ p) {
    const float4* q = (const float4*)p;
    float4 u = q[0], v = q[1];
    half8 r;
    r[0]=(_Float16)u.x; r[1]=(_Float16)u.y; r[2]=(_Float16)u.z; r[3]=(_Float16)u.w;
    r[4]=(_Float16)v.x; r[5]=(_Float16)v.y; r[6]=(_Float16)v.z; r[7]=(_Float16)v.w;
    return r;
}

// ---------------------------------------------------------------------------
// MFMA 2-layer LSTM, software-pipelined across layers (unchanged from R7).
// ---------------------------------------------------------------------------
#define SXW (TT * 8 + 8)

__global__ __launch_bounds__(512, 4)
void lstm_fused_kernel(const float* __restrict__ x,
                       const float* __restrict__ Wih0, const float* __restrict__ Whh0,
                       const float* __restrict__ bih0, const float* __restrict__ bhh0,
                       const float* __restrict__ Wih1, const float* __restrict__ Whh1,
                       const float* __restrict__ bih1, const float* __restrict__ bhh1,
                       float* __restrict__ last_out)
{
    __shared__ _Float16 sxp[16][SXW];
    __shared__ _Float16 h0buf[2][16][72];
    __shared__ _Float16 h1buf[2][16][72];
    __shared__ _Float16 zero16[8];

    const int tid  = threadIdx.x;
    const int w    = tid >> 6;
    const int grp  = w >> 2;
    const int cg   = w & 3;
    const int lane = tid & 63;
    const int quad = lane >> 4;
    const int l15  = lane & 15;
    const int hc   = cg * 16 + l15;
    const int n0   = blockIdx.x * 16;

    for (int i = tid; i < 16 * SXW / 2; i += 512) ((unsigned*)sxp)[i] = 0u;
    for (int i = tid; i < 2 * 16 * 72 / 2; i += 512) ((unsigned*)h0buf)[i] = 0u;
    for (int i = tid; i < 2 * 16 * 72 / 2; i += 512) ((unsigned*)h1buf)[i] = 0u;
    if (tid < 4) ((unsigned*)zero16)[tid] = 0u;
    __syncthreads();

    for (int idx = tid; idx < 16 * TT * DF; idx += 512) {
        const int m = idx / (TT * DF);
        const int r = idx - m * (TT * DF);
        const int t = r / DF;
        const int d = r - t * DF;
        sxp[m][t * 8 + d] = (_Float16)x[(size_t)(n0 + m) * (TT * DF) + r];
    }

    half8 wA[4][2], wB[4][2];
    float bias[4];
    half8 hzero;
    #pragma unroll
    for (int j = 0; j < 8; j++) hzero[j] = (_Float16)0.f;

    if (grp == 0) {
        #pragma unroll
        for (int nt = 0; nt < 4; nt++) {
            const int g = nt * 64 + hc;
            wA[nt][0] = ldw8(Whh0 + (size_t)g * HH + quad * 8);
            wA[nt][1] = ldw8(Whh0 + (size_t)g * HH + 32 + quad * 8);
            bias[nt]  = bih0[g] + bhh0[g];
            half8 t = hzero;
            if (quad == 0) {
                #pragma unroll
                for (int j = 0; j < DF; j++) t[j] = (_Float16)Wih0[g * DF + j];
            }
            wB[nt][0] = t;
            wB[nt][1] = hzero;
        }
    } else {
        #pragma unroll
        for (int nt = 0; nt < 4; nt++) {
            const int g = nt * 64 + hc;
            wA[nt][0] = ldw8(Wih1 + (size_t)g * HH + quad * 8);
            wA[nt][1] = ldw8(Wih1 + (size_t)g * HH + 32 + quad * 8);
            wB[nt][0] = ldw8(Whh1 + (size_t)g * HH + quad * 8);
            wB[nt][1] = ldw8(Whh1 + (size_t)g * HH + 32 + quad * 8);
            bias[nt]  = bih1[g] + bhh1[g];
        }
    }

    float cs[4] = {0.f, 0.f, 0.f, 0.f};
    __syncthreads();

    for (int i = 0; i <= TT; i++) {
        const int p = i & 1;
        if (grp == 0) {
            if (i < TT) {
                const half8 a0 = *(const half8*)&h0buf[p][l15][quad * 8];
                const half8 a1 = *(const half8*)&h0buf[p][l15][32 + quad * 8];
                const _Float16* xap = (quad == 0) ? &sxp[l15][i * 8] : zero16;
                const half8 ax = *(const half8*)xap;
                f32x4 gv[4];
                #pragma unroll
                for (int nt = 0; nt < 4; nt++) {
                    f32x4 c; c[0] = bias[nt]; c[1] = bias[nt]; c[2] = bias[nt]; c[3] = bias[nt];
                    c = MFMA16(ax, wB[nt][0], c);
                    c = MFMA16(a0, wA[nt][0], c);
                    c = MFMA16(a1, wA[nt][1], c);
                    gv[nt] = c;
                }
                _Float16 (*h0w)[72] = h0buf[p ^ 1];
                #pragma unroll
                for (int reg = 0; reg < 4; reg++) {
                    const float gi = gv[0][reg], gf = gv[1][reg], gc = gv[2][reg], go = gv[3][reg];
                    const float cc = sigmoidf_(gf) * cs[reg] + sigmoidf_(gi) * tanhf_(gc);
                    cs[reg] = cc;
                    h0w[quad * 4 + reg][hc] = (_Float16)(sigmoidf_(go) * tanhf_(cc));
                }
            }
        } else {
            if (i > 0) {
                const half8 a00 = *(const half8*)&h0buf[p][l15][quad * 8];
                const half8 a01 = *(const half8*)&h0buf[p][l15][32 + quad * 8];
                const half8 a10 = *(const half8*)&h1buf[p][l15][quad * 8];
                const half8 a11 = *(const half8*)&h1buf[p][l15][32 + quad * 8];
                f32x4 gv[4];
                #pragma unroll
                for (int nt = 0; nt < 4; nt++) {
                    f32x4 c; c[0] = bias[nt]; c[1] = bias[nt]; c[2] = bias[nt]; c[3] = bias[nt];
                    c = MFMA16(a00, wA[nt][0], c);
                    c = MFMA16(a01, wA[nt][1], c);
                    c = MFMA16(a10, wB[nt][0], c);
                    c = MFMA16(a11, wB[nt][1], c);
                    gv[nt] = c;
                }
                _Float16 (*h1w)[72] = h1buf[p ^ 1];
                #pragma unroll
                for (int reg = 0; reg < 4; reg++) {
                    const float gi = gv[0][reg], gf = gv[1][reg], gc = gv[2][reg], go = gv[3][reg];
                    const float cc = sigmoidf_(gf) * cs[reg] + sigmoidf_(gi) * tanhf_(gc);
                    cs[reg] = cc;
                    const float hv = sigmoidf_(go) * tanhf_(cc);
                    h1w[quad * 4 + reg][hc] = (_Float16)hv;
                    if (i == TT) last_out[(size_t)(n0 + quad * 4 + reg) * HH + hc] = hv;
                }
            }
        }
        __syncthreads();
    }
}

// ---------------------------------------------------------------------------
// Barrier-state init (2 ints). Runs before the tail kernel (stream-ordered).
// ---------------------------------------------------------------------------
__global__ void bar_init_kernel(int* bar) {
    if (threadIdx.x == 0) { bar[0] = 0; bar[1] = 0; }
}

// Device-scope grid barrier: release fence -> arrive; spin on generation;
// acquire fence. All 256 blocks are co-resident (1 block/CU, 52 KB LDS).
__device__ __forceinline__ void gridbar(int* __restrict__ bar) {
    __syncthreads();
    if (threadIdx.x == 0) {
        int* cnt = bar;
        int* gen = bar + 1;
        const int g = atomicAdd(gen, 0);
        __threadfence();
        if (atomicAdd(cnt, 1) == NB - 1) {
            atomicExch(cnt, 0);
            __threadfence();
            atomicAdd(gen, 1);
        } else {
            while (atomicAdd(gen, 0) == g) __builtin_amdgcn_s_sleep(8);
        }
        __threadfence();
    }
    __syncthreads();
}

// ---------------------------------------------------------------------------
// Whole GAT+FC tail in ONE persistent kernel. Grid = 256 blocks x 256 thr,
// block b owns node slice [32b, 32b+32). 6 phases, 5 grid barriers.
// Key algebra: s1_j = last_j . (Wt^T a1) + bt.a1  (hgat never materialized).
// ---------------------------------------------------------------------------
__global__ __launch_bounds__(256, 1)
void gat_tail_kernel(const float* __restrict__ last,
                     const float* __restrict__ Wt, const float* __restrict__ bt,
                     const float* __restrict__ a,
                     const float* __restrict__ Wfc, const float* __restrict__ bfc,
                     const float* __restrict__ Wout, const float* __restrict__ bout,
                     float* __restrict__ blkmax, float* __restrict__ Dj,
                     float* __restrict__ sortedRow, float* __restrict__ sortedD,
                     float* __restrict__ chunkSum, float* __restrict__ PP,
                     int* __restrict__ bar,
                     float* __restrict__ out)
{
    __shared__ float big[NN];          // 32 KB: Dj stage (P2), sortedD stage (P5)
    __shared__ float sWfc[HH][HH + 1]; // 16.25 KB, transposed Wfc
    __shared__ float sv1[HH], sv2[HH], sbF[HH], saF[HH];
    __shared__ float sc12[2];
    __shared__ float sS1[32], sS2[32], sZ[32], sAi[32], sBi[32], sU[32], sWw[32], sD[32];
    __shared__ int   sRank[32];
    __shared__ float sred[256];

    const int tid  = threadIdx.x;
    const int b    = blockIdx.x;
    const int j0   = b * 32;
    const int wv   = tid >> 6;
    const int lane = tid & 63;

    // ================= P0: v1/v2/c1/c2, FC staging, s1/s2, block max ========
    for (int idx = tid; idx < HH * HH; idx += 256) {
        const int h = idx >> 6, d = idx & 63;
        sWfc[d][h] = Wfc[idx];
    }
    if (tid < HH) {
        float a1 = 0.f, a2 = 0.f;
        #pragma unroll 8
        for (int h = 0; h < HH; h++) {
            const float wt = Wt[h * HH + tid];
            a1 += wt * a[h];
            a2 += wt * a[HH + h];
        }
        sv1[tid] = a1; sv2[tid] = a2;
    } else if (tid == 64 || tid == 65) {
        const float* av = a + (tid - 64) * HH;
        float c = 0.f;
        #pragma unroll 8
        for (int h = 0; h < HH; h++) c += bt[h] * av[h];
        sc12[tid - 64] = c;
    } else if (tid >= 128 && tid < 192) {
        sbF[tid - 128] = bfc[tid - 128];
    } else if (tid >= 192) {
        saF[tid - 192] = Wout[tid - 192];
    }
    __syncthreads();

    #pragma unroll
    for (int jj = 0; jj < 8; jj++) {
        const int jl = wv * 8 + jj;
        const float lv = last[(size_t)(j0 + jl) * HH + lane];
        float p1 = lv * sv1[lane];
        float p2 = lv * sv2[lane];
        #pragma unroll
        for (int off = 32; off > 0; off >>= 1) {
            p1 += __shfl_xor(p1, off);
            p2 += __shfl_xor(p2, off);
        }
        if (lane == 0) { sS1[jl] = p1 + sc12[0]; sS2[jl] = p2 + sc12[1]; }
    }
    __syncthreads();
    if (tid < 32) {
        float m = sS1[tid];
        #pragma unroll
        for (int off = 16; off > 0; off >>= 1) m = fmaxf(m, __shfl_xor(m, off));
        if (tid == 0) blkmax[b] = m;
    }
    gridbar(bar);

    // ================= P1: s1max; per-node factors (slice-local) ============
    sred[tid] = blkmax[tid];
    __syncthreads();
    for (int s = 128; s > 0; s >>= 1) {
        if (tid < s) sred[tid] = fmaxf(sred[tid], sred[tid + s]);
        __syncthreads();
    }
    const float s1max = sred[0];
    if (tid < 32) {
        const float z  = sS2[tid] + s1max;
        const float mi = lrelu_(z);
        sZ[tid]  = z;
        sAi[tid] = __expf(z - mi);
        sBi[tid] = __expf(0.01f * z - mi);
        const float d = sS1[tid] - s1max;
        sD[tid] = d;
        Dj[j0 + tid] = d;
        sU[tid]  = __expf(d);
        sWw[tid] = __expf(0.01f * d);
        sRank[tid] = 0;
    }
    gridbar(bar);

    // ================= P2: rank (slice-local) + scatter =====================
    for (int idx = tid; idx < NN; idx += 256) big[idx] = Dj[idx];
    __syncthreads();
    {
        const int jl = tid & 31;
        const int part = tid >> 5;            // 0..7
        const float dj = sD[jl];
        const int jglob = j0 + jl;
        int cnt = 0;
        const int k0 = part * (NN / 8);
        #pragma unroll 4
        for (int k = k0; k < k0 + NN / 8; k++) {
            const float dk = big[k];
            cnt += (dk < dj || (dk == dj && k < jglob)) ? 1 : 0;
        }
        atomicAdd(&sRank[jl], cnt);
    }
    __syncthreads();
    #pragma unroll
    for (int jj = 0; jj < 8; jj++) {
        const int jl = wv * 8 + jj;
        const int r = sRank[jl];
        const float u = sU[jl], w = sWw[jl];
        const float lv = last[(size_t)(j0 + jl) * HH + lane];
        float* row = sortedRow + (size_t)r * RS;
        row[lane]      = u * lv;
        row[64 + lane] = w * lv;
        if (lane == 0) {
            row[128] = u;
            row[129] = w;
            sortedD[r] = sD[jl];
        }
    }
    gridbar(bar);

    // ================= P3: chunk column sums ================================
    if (tid < 130) {
        const float* base = sortedRow + (size_t)b * CH * RS + tid;
        float s = 0.f;
        #pragma unroll 8
        for (int r = 0; r < CH; r++) s += base[(size_t)r * RS];
        chunkSum[b * RS + tid] = s;
    }
    gridbar(bar);

    // ================= P4: fill PP (prefix for W-group, suffix for U-group) =
    if (tid < 130) {
        const int c = tid;
        const bool rev = (c < 64) || (c == 128);
        float run = 0.f;
        #pragma unroll 8
        for (int bb = 0; bb < NB; bb++) {
            const float v = chunkSum[bb * RS + c];
            run += ((rev ? (bb > b) : (bb < b)) ? v : 0.f);
        }
        if (rev) {
            if (b == NB - 1) PP[(size_t)NN * RS + c] = 0.f;
            #pragma unroll 4
            for (int r = CH - 1; r >= 0; r--) {
                const size_t t = (size_t)b * CH + r;
                run += sortedRow[t * RS + c];
                PP[t * RS + c] = run;
            }
        } else {
            #pragma unroll 4
            for (int r = 0; r < CH; r++) {
                const size_t t = (size_t)b * CH + r;
                PP[t * RS + c] = run;
                run += sortedRow[t * RS + c];
            }
            if (b == NB - 1) PP[(size_t)NN * RS + c] = run;
        }
    }
    gridbar(bar);

    // ================= P5: apply + FC head (slice-local) ====================
    for (int idx = tid; idx < NN; idx += 256) big[idx] = sortedD[idx];
    __syncthreads();
    const float bo = bout[0];
    #pragma unroll
    for (int jj = 0; jj < 8; jj++) {
        const int il = wv * 8 + jj;
        const int i  = j0 + il;
        const float zi = sZ[il];
        int lo = 0, hi = NN;
        #pragma unroll
        for (int iter = 0; iter < 13; iter++) {
            const int mid = (lo + hi) >> 1;
            const float dm = big[mid];
            if (zi + dm > 0.f) hi = mid; else lo = mid + 1;
        }
        const float* rowp = PP + (size_t)lo * RS;
        const float pu  = rowp[lane];
        const float pw  = rowp[64 + lane];
        const float pud = rowp[128];
        const float pwd = rowp[129];
        const float ai = sAi[il], bi = sBi[il];
        const float numer = bi * pw + ai * pu;
        const float den   = bi * pwd + ai * pud;
        const float lv = last[(size_t)i * HH + lane];
        const float gv = numer * __builtin_amdgcn_rcpf(den) + lv;
        float acc = sbF[lane];
        #pragma unroll
        for (int d = 0; d < HH; d++) acc += __shfl(gv, d) * sWfc[d][lane];
        float prod = lrelu_(acc) * saF[lane];
        #pragma unroll
        for (int off = 32; off > 0; off >>= 1) prod += __shfl_xor(prod, off);
        if (lane == 0) out[i] = prod + bo;
    }
}

extern "C" void kernel_launch(void* const* d_in, const int* in_sizes, int n_in,
                              void* d_out, int out_size, void* d_ws, size_t ws_size,
                              hipStream_t stream)
{
    (void)in_sizes; (void)n_in; (void)out_size; (void)ws_size;
    const float* x    = (const float*)d_in[0];
    const float* Wih0 = (const float*)d_in[1];
    const float* Whh0 = (const float*)d_in[2];
    const float* bih0 = (const float*)d_in[3];
    const float* bhh0 = (const float*)d_in[4];
    const float* Wih1 = (const float*)d_in[5];
    const float* Whh1 = (const float*)d_in[6];
    const float* bih1 = (const float*)d_in[7];
    const float* bhh1 = (const float*)d_in[8];
    const float* Wt   = (const float*)d_in[9];
    const float* bt   = (const float*)d_in[10];
    const float* a    = (const float*)d_in[11];
    const float* Wfc  = (const float*)d_in[12];
    const float* bfc  = (const float*)d_in[13];
    const float* Wout = (const float*)d_in[14];
    const float* bout = (const float*)d_in[15];
    float* out = (float*)d_out;

    float* ws        = (float*)d_ws;
    float* last      = ws;                          // N*H
    float* Dj        = last + (size_t)NN*HH;        // N
    float* blkmax    = Dj + NN;                     // 256
    float* sortedD   = blkmax + 256;                // N
    float* sortedRow = sortedD + NN;                // N*RS
    float* PP        = sortedRow + (size_t)NN*RS;   // (N+1)*RS
    float* chunkSum  = PP + (size_t)(NN+1)*RS;      // NB*RS
    int*   bar       = (int*)(chunkSum + NB*RS);    // 2 ints

    lstm_fused_kernel<<<dim3(NN / 16), dim3(512), 0, stream>>>(
        x, Wih0, Whh0, bih0, bhh0, Wih1, Whh1, bih1, bhh1, last);
    bar_init_kernel<<<dim3(1), dim3(64), 0, stream>>>(bar);
    gat_tail_kernel<<<dim3(NB), dim3(256), 0, stream>>>(
        last, Wt, bt, a, Wfc, bfc, Wout, bout,
        blkmax, Dj, sortedRow, sortedD, chunkSum, PP, bar, out);
}